// Round 1
// baseline (5413.241 us; speedup 1.0000x reference)
//
#include <hip/hip_runtime.h>
#include <math.h>

#define SEQLEN 1024
#define DIM 512
#define MM 512

__device__ __forceinline__ float sigf(float x) { return 1.0f / (1.0f + expf(-x)); }

// ---------------- K1: Gx[seq][t][g] = emb[ids[t]] . Wxcat[g] + bias_cat[g] ----------------
// Wxcat rows: [Wioux (1536 rows); Wfx (512 rows)], 512 cols.  Gx: [2][1024][2048]
__global__ __launch_bounds__(256) void gx_gemm(
    const int* __restrict__ l_ids, const int* __restrict__ r_ids,
    const float* __restrict__ emb,
    const float* __restrict__ Wioux, const float* __restrict__ Wfx,
    const float* __restrict__ bioux, const float* __restrict__ biouh,
    const float* __restrict__ bfx, const float* __restrict__ bfh,
    float* __restrict__ gx)
{
  __shared__ __align__(16) float At[32][68];   // transposed tiles: [k][row]
  __shared__ __align__(16) float Bt[32][68];
  const int tid = threadIdx.x;
  const int bid = blockIdx.x;
  const int seq = bid >> 9;            // 2
  const int tt  = (bid >> 5) & 15;     // 16 t-tiles of 64
  const int gt  = bid & 31;            // 32 g-tiles of 64
  const int t0 = tt * 64, g0 = gt * 64;
  const int* ids = seq ? r_ids : l_ids;

  const int li = tid >> 2;             // 0..63 (tile row)
  const int lk = (tid & 3) * 8;        // k chunk
  const float* arow = emb + (size_t)ids[t0 + li] * DIM;
  const int gg = g0 + li;
  const float* brow = (gg < 1536) ? (Wioux + (size_t)gg * DIM)
                                  : (Wfx + (size_t)(gg - 1536) * DIM);
  const int tr = tid >> 4;             // 0..15 micro-row group
  const int tc = tid & 15;             // 0..15 micro-col group

  float acc[4][4];
  #pragma unroll
  for (int i = 0; i < 4; ++i) { acc[i][0]=0.f; acc[i][1]=0.f; acc[i][2]=0.f; acc[i][3]=0.f; }

  for (int kb = 0; kb < 16; ++kb) {
    const int k0 = kb * 32;
    float4 av0 = *(const float4*)(arow + k0 + lk);
    float4 av1 = *(const float4*)(arow + k0 + lk + 4);
    float4 bv0 = *(const float4*)(brow + k0 + lk);
    float4 bv1 = *(const float4*)(brow + k0 + lk + 4);
    __syncthreads();
    At[lk+0][li]=av0.x; At[lk+1][li]=av0.y; At[lk+2][li]=av0.z; At[lk+3][li]=av0.w;
    At[lk+4][li]=av1.x; At[lk+5][li]=av1.y; At[lk+6][li]=av1.z; At[lk+7][li]=av1.w;
    Bt[lk+0][li]=bv0.x; Bt[lk+1][li]=bv0.y; Bt[lk+2][li]=bv0.z; Bt[lk+3][li]=bv0.w;
    Bt[lk+4][li]=bv1.x; Bt[lk+5][li]=bv1.y; Bt[lk+6][li]=bv1.z; Bt[lk+7][li]=bv1.w;
    __syncthreads();
    #pragma unroll
    for (int k = 0; k < 32; ++k) {
      float4 a4 = *(const float4*)&At[k][tr*4];
      float4 b4 = *(const float4*)&Bt[k][tc*4];
      acc[0][0]+=a4.x*b4.x; acc[0][1]+=a4.x*b4.y; acc[0][2]+=a4.x*b4.z; acc[0][3]+=a4.x*b4.w;
      acc[1][0]+=a4.y*b4.x; acc[1][1]+=a4.y*b4.y; acc[1][2]+=a4.y*b4.z; acc[1][3]+=a4.y*b4.w;
      acc[2][0]+=a4.z*b4.x; acc[2][1]+=a4.z*b4.y; acc[2][2]+=a4.z*b4.z; acc[2][3]+=a4.z*b4.w;
      acc[3][0]+=a4.w*b4.x; acc[3][1]+=a4.w*b4.y; acc[3][2]+=a4.w*b4.z; acc[3][3]+=a4.w*b4.w;
    }
  }
  const int gc = g0 + tc * 4;
  float badd[4];
  #pragma unroll
  for (int jj = 0; jj < 4; ++jj) {
    int g = gc + jj;
    badd[jj] = (g < 1536) ? (bioux[g] + biouh[g]) : (bfx[g-1536] + bfh[g-1536]);
  }
  #pragma unroll
  for (int ii = 0; ii < 4; ++ii) {
    float4 r;
    r.x = acc[ii][0] + badd[0];
    r.y = acc[ii][1] + badd[1];
    r.z = acc[ii][2] + badd[2];
    r.w = acc[ii][3] + badd[3];
    size_t off = ((size_t)seq * SEQLEN + (size_t)(t0 + tr*4 + ii)) * 2048 + gc;
    *(float4*)(gx + off) = r;
  }
}

// ---------------- K2: persistent recurrent scan, 32 WGs, weights in VGPRs ----------------
// WG wg owns m in [wg*16, wg*16+16). Rows rr = gate*16 + j (gate 0..3 = i,o,u,f).
// Thread (a = tid>>4, b = tid&15): rows a*4..a*4+3, cols [b*32, b*32+32).
__global__ __launch_bounds__(256, 1) void lstm_scan(
    const float* __restrict__ Wiouh, const float* __restrict__ Wfh,
    const float* __restrict__ gx,
    float* __restrict__ hbuf,       // [2 parity][2 seq][512]
    float* __restrict__ hB,         // [2 seq][512]
    unsigned* __restrict__ done)    // [32] per-WG step counters (zeroed by memset)
{
  const int tid = threadIdx.x;
  const int wg = blockIdx.x;       // 0..31
  const int a = tid >> 4;          // 0..15
  const int b = tid & 15;          // 0..15

  float w[4][32];
  #pragma unroll
  for (int r = 0; r < 4; ++r) {
    const int rr = a*4 + r;
    const int gate = rr >> 4;
    const int j = rr & 15;
    const float* row = (gate < 3) ? (Wiouh + (size_t)(gate*512 + wg*16 + j) * MM)
                                  : (Wfh + (size_t)(wg*16 + j) * MM);
    #pragma unroll
    for (int q = 0; q < 8; ++q) {
      float4 v = *(const float4*)(row + b*32 + q*4);
      w[r][q*4+0]=v.x; w[r][q*4+1]=v.y; w[r][q*4+2]=v.z; w[r][q*4+3]=v.w;
    }
  }

  __shared__ float pre[2][64];
  float cst = 0.0f;   // persistent c state for update threads (tid < 32)

  for (int t = 0; t < SEQLEN; ++t) {
    const float* hcur = hbuf + (t & 1) * 1024;
    float hlf[32], hrf[32];
    #pragma unroll
    for (int q = 0; q < 8; ++q) {
      float4 vl = *(const float4*)(hcur + b*32 + q*4);
      float4 vr = *(const float4*)(hcur + 512 + b*32 + q*4);
      hlf[q*4+0]=vl.x; hlf[q*4+1]=vl.y; hlf[q*4+2]=vl.z; hlf[q*4+3]=vl.w;
      hrf[q*4+0]=vr.x; hrf[q*4+1]=vr.y; hrf[q*4+2]=vr.z; hrf[q*4+3]=vr.w;
    }
    float4 gxl, gxr;
    if (b == 0) {   // x-part + bias for rows a*4..a*4+3: 4 consecutive g indices
      const int gbase = (a >> 2) * 512 + wg*16 + (a & 3) * 4;
      gxl = *(const float4*)(gx + (size_t)t * 2048 + gbase);
      gxr = *(const float4*)(gx + ((size_t)SEQLEN + t) * 2048 + gbase);
    }
    float accl[4] = {0,0,0,0}, accr[4] = {0,0,0,0};
    #pragma unroll
    for (int k = 0; k < 32; ++k) {
      accl[0] += w[0][k]*hlf[k];
      accl[1] += w[1][k]*hlf[k];
      accl[2] += w[2][k]*hlf[k];
      accl[3] += w[3][k]*hlf[k];
      accr[0] += w[0][k]*hrf[k];
      accr[1] += w[1][k]*hrf[k];
      accr[2] += w[2][k]*hrf[k];
      accr[3] += w[3][k]*hrf[k];
    }
    #pragma unroll
    for (int msk = 1; msk < 16; msk <<= 1) {
      #pragma unroll
      for (int r = 0; r < 4; ++r) {
        accl[r] += __shfl_xor(accl[r], msk, 64);
        accr[r] += __shfl_xor(accr[r], msk, 64);
      }
    }
    if (b == 0) {
      pre[0][a*4+0] = accl[0] + gxl.x;
      pre[0][a*4+1] = accl[1] + gxl.y;
      pre[0][a*4+2] = accl[2] + gxl.z;
      pre[0][a*4+3] = accl[3] + gxl.w;
      pre[1][a*4+0] = accr[0] + gxr.x;
      pre[1][a*4+1] = accr[1] + gxr.y;
      pre[1][a*4+2] = accr[2] + gxr.z;
      pre[1][a*4+3] = accr[3] + gxr.w;
    }
    __syncthreads();
    if (tid < 32) {
      const int seq = tid >> 4;
      const int j = tid & 15;
      const float iv = pre[seq][j];
      const float ov = pre[seq][16+j];
      const float uv = pre[seq][32+j];
      const float fv = pre[seq][48+j];
      cst = sigf(iv) * tanhf(uv) + sigf(fv) * cst;
      const float h2 = sigf(ov) * tanhf(cst);
      hbuf[((t+1)&1)*1024 + seq*512 + wg*16 + j] = h2;
      if (t == SEQLEN-1) {
        // hB = cell(x_last, 0, 0).h : pre = Gx only (h = 0, c = 0)
        const float* gq = gx + ((size_t)seq * SEQLEN + (SEQLEN-1)) * 2048 + wg*16 + j;
        const float cB = sigf(gq[0]) * tanhf(gq[1024]);
        hB[seq*512 + wg*16 + j] = sigf(gq[512]) * tanhf(cB);
      }
      __threadfence();   // release h2 stores to device scope
    }
    __syncthreads();
    if (tid == 0)
      __hip_atomic_store(&done[wg], (unsigned)(t+1), __ATOMIC_RELEASE, __HIP_MEMORY_SCOPE_AGENT);
    if (tid < 64) {      // wave 0 polls all 32 slots in parallel (no atomic contention)
      const unsigned target = (unsigned)(t+1);
      for (;;) {
        unsigned v = 0xFFFFFFFFu;
        if (tid < 32) v = __hip_atomic_load(&done[tid], __ATOMIC_RELAXED, __HIP_MEMORY_SCOPE_AGENT);
        if (__all((int)(v >= target))) break;
        __builtin_amdgcn_s_sleep(1);
      }
      __threadfence();   // acquire: invalidate L1/L2 before next step's h loads
    }
    __syncthreads();
  }
}

// ---------------- K3a: s = sigmoid(Wh @ vec + bh), 16 WGs x 16 rows ----------------
__global__ __launch_bounds__(256) void head1(
    const float* __restrict__ hbuf, const float* __restrict__ hB,
    const float* __restrict__ Wh, const float* __restrict__ bh,
    float* __restrict__ sv)
{
  __shared__ __align__(16) float vec[2048];
  const int tid = threadIdx.x;
  const int wg = blockIdx.x;  // 0..15
  for (int k = tid; k < 1024; k += 256) {
    const float lv = (k < 512) ? hbuf[k]       : hB[k - 512];
    const float rv = (k < 512) ? hbuf[512 + k] : hB[512 + (k - 512)];
    vec[k] = lv * rv;
    vec[1024 + k] = fabsf(lv - rv);
  }
  __syncthreads();
  const int row = wg * 16 + (tid >> 4);
  const int ln = tid & 15;
  const float* wr = Wh + (size_t)row * 2048 + ln * 128;
  const float* vp = vec + ln * 128;
  float acc = 0.0f;
  #pragma unroll
  for (int k = 0; k < 128; k += 4) {
    float4 wv = *(const float4*)(wr + k);
    float4 vv = *(const float4*)(vp + k);
    acc += wv.x*vv.x + wv.y*vv.y + wv.z*vv.z + wv.w*vv.w;
  }
  #pragma unroll
  for (int msk = 1; msk < 16; msk <<= 1) acc += __shfl_xor(acc, msk, 64);
  if (ln == 0) sv[row] = 1.0f / (1.0f + expf(-(acc + bh[row])));
}

// ---------------- K3b: logits = Wp @ s + bp ; log_softmax ----------------
__global__ __launch_bounds__(256) void head2(
    const float* __restrict__ sv, const float* __restrict__ Wp,
    const float* __restrict__ bp, float* __restrict__ out)
{
  __shared__ float s_l[256];
  __shared__ float lg[5];
  const int tid = threadIdx.x;
  s_l[tid] = sv[tid];
  __syncthreads();
  if (tid < 5) {
    float acc = bp[tid];
    for (int k = 0; k < 256; ++k) acc += Wp[tid*256 + k] * s_l[k];
    lg[tid] = acc;
  }
  __syncthreads();
  if (tid == 0) {
    float mx = lg[0];
    #pragma unroll
    for (int i = 1; i < 5; ++i) mx = fmaxf(mx, lg[i]);
    float sum = 0.0f;
    #pragma unroll
    for (int i = 0; i < 5; ++i) sum += expf(lg[i] - mx);
    const float lse = mx + logf(sum);
    #pragma unroll
    for (int i = 0; i < 5; ++i) out[i] = lg[i] - lse;
  }
}

extern "C" void kernel_launch(void* const* d_in, const int* in_sizes, int n_in,
                              void* d_out, int out_size, void* d_ws, size_t ws_size,
                              hipStream_t stream) {
  const int*   l_ids = (const int*)d_in[0];
  const int*   r_ids = (const int*)d_in[1];
  const float* emb   = (const float*)d_in[2];
  const float* Wioux = (const float*)d_in[3];
  const float* bioux = (const float*)d_in[4];
  const float* Wiouh = (const float*)d_in[5];
  const float* biouh = (const float*)d_in[6];
  const float* Wfx   = (const float*)d_in[7];
  const float* bfx   = (const float*)d_in[8];
  const float* Wfh   = (const float*)d_in[9];
  const float* bfh   = (const float*)d_in[10];
  const float* Wh    = (const float*)d_in[11];
  const float* bh    = (const float*)d_in[12];
  const float* Wp    = (const float*)d_in[13];
  const float* bp    = (const float*)d_in[14];
  float* out = (float*)d_out;

  // workspace layout (floats): Gx [2*1024*2048], hbuf [2048], hB [1024], sv [256], done [32]
  float* gx   = (float*)d_ws;
  float* hbuf = gx + (size_t)2*1024*2048;
  float* hB   = hbuf + 2048;
  float* sv   = hB + 1024;
  unsigned* done = (unsigned*)(sv + 256);

  // zero h(t=0), hB, sv, done each launch (graph-captured as a memset node)
  hipMemsetAsync(hbuf, 0, (2048 + 1024 + 256 + 32) * sizeof(float), stream);

  gx_gemm<<<dim3(1024), dim3(256), 0, stream>>>(l_ids, r_ids, emb, Wioux, Wfx,
                                                bioux, biouh, bfx, bfh, gx);
  lstm_scan<<<dim3(32), dim3(256), 0, stream>>>(Wiouh, Wfh, gx, hbuf, hB, done);
  head1<<<dim3(16), dim3(256), 0, stream>>>(hbuf, hB, Wh, bh, sv);
  head2<<<dim3(1), dim3(256), 0, stream>>>(sv, Wp, bp, out);
  (void)in_sizes; (void)n_in; (void)out_size; (void)ws_size;
}

// Round 2
// 2348.010 us; speedup vs baseline: 2.3055x; 2.3055x over previous
//
#include <hip/hip_runtime.h>
#include <math.h>

#define SEQLEN 1024
#define DIM 512
#define MM 512

typedef float f32x4 __attribute__((ext_vector_type(4)));
typedef float f32x2 __attribute__((ext_vector_type(2)));

__device__ __forceinline__ float sigf(float x) { return 1.0f / (1.0f + expf(-x)); }

// ---------------- K1: Gx[seq][t][g] = emb[ids[t]] . Wxcat[g] + bias_cat[g] ----------------
// Wxcat rows: [Wioux (1536 rows); Wfx (512 rows)], 512 cols.  Gx: [2][1024][2048]
__global__ __launch_bounds__(256) void gx_gemm(
    const int* __restrict__ l_ids, const int* __restrict__ r_ids,
    const float* __restrict__ emb,
    const float* __restrict__ Wioux, const float* __restrict__ Wfx,
    const float* __restrict__ bioux, const float* __restrict__ biouh,
    const float* __restrict__ bfx, const float* __restrict__ bfh,
    float* __restrict__ gx)
{
  __shared__ __align__(16) float At[32][68];   // transposed tiles: [k][row]
  __shared__ __align__(16) float Bt[32][68];
  const int tid = threadIdx.x;
  const int bid = blockIdx.x;
  const int seq = bid >> 9;            // 2
  const int tt  = (bid >> 5) & 15;     // 16 t-tiles of 64
  const int gt  = bid & 31;            // 32 g-tiles of 64
  const int t0 = tt * 64, g0 = gt * 64;
  const int* ids = seq ? r_ids : l_ids;

  const int li = tid >> 2;             // 0..63 (tile row)
  const int lk = (tid & 3) * 8;        // k chunk
  const float* arow = emb + (size_t)ids[t0 + li] * DIM;
  const int gg = g0 + li;
  const float* brow = (gg < 1536) ? (Wioux + (size_t)gg * DIM)
                                  : (Wfx + (size_t)(gg - 1536) * DIM);
  const int tr = tid >> 4;             // 0..15 micro-row group
  const int tc = tid & 15;             // 0..15 micro-col group

  float acc[4][4];
  #pragma unroll
  for (int i = 0; i < 4; ++i) { acc[i][0]=0.f; acc[i][1]=0.f; acc[i][2]=0.f; acc[i][3]=0.f; }

  for (int kb = 0; kb < 16; ++kb) {
    const int k0 = kb * 32;
    float4 av0 = *(const float4*)(arow + k0 + lk);
    float4 av1 = *(const float4*)(arow + k0 + lk + 4);
    float4 bv0 = *(const float4*)(brow + k0 + lk);
    float4 bv1 = *(const float4*)(brow + k0 + lk + 4);
    __syncthreads();
    At[lk+0][li]=av0.x; At[lk+1][li]=av0.y; At[lk+2][li]=av0.z; At[lk+3][li]=av0.w;
    At[lk+4][li]=av1.x; At[lk+5][li]=av1.y; At[lk+6][li]=av1.z; At[lk+7][li]=av1.w;
    Bt[lk+0][li]=bv0.x; Bt[lk+1][li]=bv0.y; Bt[lk+2][li]=bv0.z; Bt[lk+3][li]=bv0.w;
    Bt[lk+4][li]=bv1.x; Bt[lk+5][li]=bv1.y; Bt[lk+6][li]=bv1.z; Bt[lk+7][li]=bv1.w;
    __syncthreads();
    #pragma unroll
    for (int k = 0; k < 32; ++k) {
      float4 a4 = *(const float4*)&At[k][tr*4];
      float4 b4 = *(const float4*)&Bt[k][tc*4];
      acc[0][0]+=a4.x*b4.x; acc[0][1]+=a4.x*b4.y; acc[0][2]+=a4.x*b4.z; acc[0][3]+=a4.x*b4.w;
      acc[1][0]+=a4.y*b4.x; acc[1][1]+=a4.y*b4.y; acc[1][2]+=a4.y*b4.z; acc[1][3]+=a4.y*b4.w;
      acc[2][0]+=a4.z*b4.x; acc[2][1]+=a4.z*b4.y; acc[2][2]+=a4.z*b4.z; acc[2][3]+=a4.z*b4.w;
      acc[3][0]+=a4.w*b4.x; acc[3][1]+=a4.w*b4.y; acc[3][2]+=a4.w*b4.z; acc[3][3]+=a4.w*b4.w;
    }
  }
  const int gc = g0 + tc * 4;
  float badd[4];
  #pragma unroll
  for (int jj = 0; jj < 4; ++jj) {
    int g = gc + jj;
    badd[jj] = (g < 1536) ? (bioux[g] + biouh[g]) : (bfx[g-1536] + bfh[g-1536]);
  }
  #pragma unroll
  for (int ii = 0; ii < 4; ++ii) {
    float4 r;
    r.x = acc[ii][0] + badd[0];
    r.y = acc[ii][1] + badd[1];
    r.z = acc[ii][2] + badd[2];
    r.w = acc[ii][3] + badd[3];
    size_t off = ((size_t)seq * SEQLEN + (size_t)(t0 + tr*4 + ii)) * 2048 + gc;
    *(float4*)(gx + off) = r;
  }
}

// ---------------- K2: persistent recurrent scan, 32 WGs, weights in VGPRs ----------------
// h exchanged as {value, tag} float2 pairs, per-access coherent (sc0 sc1) — NO cache-wide
// fences. hbuf2: [2 parity][1024 entries][2]; entry e = seq*512 + j.
// WG wg owns h-indices [wg*16, wg*16+16). Thread (a=tid>>4, b=tid&15): gate-rows a*4..a*4+3,
// h-cols [b*32, b*32+32).
#define HPAD(e) ((e) + (((e) >> 5) << 2))   // pad +4 floats per 32 -> kills bank conflicts

__global__ __launch_bounds__(256, 1) void lstm_scan(
    const float* __restrict__ Wiouh, const float* __restrict__ Wfh,
    const float* __restrict__ gx,
    float* __restrict__ hbuf2,      // [2][1024][2] {val, tag}, zeroed by memset
    float* __restrict__ hB)         // [2 seq][512]
{
  const int tid = threadIdx.x;
  const int wg = blockIdx.x;       // 0..31
  const int a = tid >> 4;          // 0..15
  const int b = tid & 15;          // 0..15

  float w[4][32];
  #pragma unroll
  for (int r = 0; r < 4; ++r) {
    const int rr = a*4 + r;
    const int gate = rr >> 4;
    const int j = rr & 15;
    const float* row = (gate < 3) ? (Wiouh + (size_t)(gate*512 + wg*16 + j) * MM)
                                  : (Wfh + (size_t)(wg*16 + j) * MM);
    #pragma unroll
    for (int q = 0; q < 8; ++q) {
      float4 v = *(const float4*)(row + b*32 + q*4);
      w[r][q*4+0]=v.x; w[r][q*4+1]=v.y; w[r][q*4+2]=v.z; w[r][q*4+3]=v.w;
    }
  }

  __shared__ __align__(16) float hsm[1152];   // padded h staging (1024 + 32*4)
  __shared__ float pre[2][64];
  float cst = 0.0f;   // persistent c state for update threads (tid < 32)

  for (int t = 0; t < SEQLEN; ++t) {
    // ---- poll + load the 4 h entries this thread stages (coherent, bypass L1/L2) ----
    {
      const float* pp = hbuf2 + ((size_t)((t & 1) * 1024 + tid * 4)) * 2;
      const float tf = (float)t;
      f32x4 r0, r1;
      for (;;) {
        asm volatile("global_load_dwordx4 %0, %2, off sc0 sc1\n\t"
                     "global_load_dwordx4 %1, %3, off sc0 sc1\n\t"
                     "s_waitcnt vmcnt(0)"
                     : "=&v"(r0), "=&v"(r1)
                     : "v"(pp), "v"(pp + 4)
                     : "memory");
        if (r0[1] >= tf && r0[3] >= tf && r1[1] >= tf && r1[3] >= tf) break;
        __builtin_amdgcn_s_sleep(1);
      }
      const int e0 = tid * 4;
      f32x4 hv; hv[0]=r0[0]; hv[1]=r0[2]; hv[2]=r1[0]; hv[3]=r1[2];
      *(f32x4*)&hsm[HPAD(e0)] = hv;
    }
    float4 gxl, gxr;
    if (b == 0) {   // x-part + bias for rows a*4..a*4+3: 4 consecutive g indices
      const int gbase = (a >> 2) * 512 + wg*16 + (a & 3) * 4;
      gxl = *(const float4*)(gx + (size_t)t * 2048 + gbase);
      gxr = *(const float4*)(gx + ((size_t)SEQLEN + t) * 2048 + gbase);
    }
    __syncthreads();

    // ---- GEMV: stage h from LDS, 2-way-bank-conflict-free ----
    float hlf[32], hrf[32];
    #pragma unroll
    for (int q = 0; q < 8; ++q) {
      f32x4 vl = *(const f32x4*)&hsm[b*36 + q*4];          // HPAD(b*32+q*4)
      f32x4 vr = *(const f32x4*)&hsm[576 + b*36 + q*4];    // HPAD(512+b*32+q*4)
      hlf[q*4+0]=vl[0]; hlf[q*4+1]=vl[1]; hlf[q*4+2]=vl[2]; hlf[q*4+3]=vl[3];
      hrf[q*4+0]=vr[0]; hrf[q*4+1]=vr[1]; hrf[q*4+2]=vr[2]; hrf[q*4+3]=vr[3];
    }
    float accl[4] = {0,0,0,0}, accr[4] = {0,0,0,0};
    #pragma unroll
    for (int k = 0; k < 32; ++k) {
      accl[0] += w[0][k]*hlf[k];
      accl[1] += w[1][k]*hlf[k];
      accl[2] += w[2][k]*hlf[k];
      accl[3] += w[3][k]*hlf[k];
      accr[0] += w[0][k]*hrf[k];
      accr[1] += w[1][k]*hrf[k];
      accr[2] += w[2][k]*hrf[k];
      accr[3] += w[3][k]*hrf[k];
    }
    #pragma unroll
    for (int msk = 1; msk < 16; msk <<= 1) {
      #pragma unroll
      for (int r = 0; r < 4; ++r) {
        accl[r] += __shfl_xor(accl[r], msk, 64);
        accr[r] += __shfl_xor(accr[r], msk, 64);
      }
    }
    if (b == 0) {
      pre[0][a*4+0] = accl[0] + gxl.x;
      pre[0][a*4+1] = accl[1] + gxl.y;
      pre[0][a*4+2] = accl[2] + gxl.z;
      pre[0][a*4+3] = accl[3] + gxl.w;
      pre[1][a*4+0] = accr[0] + gxr.x;
      pre[1][a*4+1] = accr[1] + gxr.y;
      pre[1][a*4+2] = accr[2] + gxr.z;
      pre[1][a*4+3] = accr[3] + gxr.w;
    }
    __syncthreads();

    // ---- cell update + coherent publish {h2, tag} ----
    if (tid < 32) {
      const int seq = tid >> 4;
      const int j = tid & 15;
      const float iv = pre[seq][j];
      const float ov = pre[seq][16+j];
      const float uv = pre[seq][32+j];
      const float fv = pre[seq][48+j];
      cst = sigf(iv) * tanhf(uv) + sigf(fv) * cst;
      const float h2 = sigf(ov) * tanhf(cst);
      float* dp = hbuf2 + ((size_t)(((t+1) & 1) * 1024 + seq*512 + wg*16 + j)) * 2;
      f32x2 st; st[0] = h2; st[1] = (float)(t+1);
      asm volatile("global_store_dwordx2 %0, %1, off sc0 sc1" :: "v"(dp), "v"(st) : "memory");
      if (t == SEQLEN-1) {
        // hB = cell(x_last, 0, 0).h : pre = Gx only (h = 0, c = 0)
        const float* gq = gx + ((size_t)seq * SEQLEN + (SEQLEN-1)) * 2048 + wg*16 + j;
        const float cB = sigf(gq[0]) * tanhf(gq[1024]);
        hB[seq*512 + wg*16 + j] = sigf(gq[512]) * tanhf(cB);
      }
    }
    // no barrier needed here: next iteration's hsm writes come only after every
    // thread passed this iteration's second __syncthreads (GEMV reads done)
  }
}

// ---------------- K3a: s = sigmoid(Wh @ vec + bh), 16 WGs x 16 rows ----------------
__global__ __launch_bounds__(256) void head1(
    const float* __restrict__ hbuf2, const float* __restrict__ hB,
    const float* __restrict__ Wh, const float* __restrict__ bh,
    float* __restrict__ sv)
{
  __shared__ __align__(16) float vec[2048];
  const int tid = threadIdx.x;
  const int wg = blockIdx.x;  // 0..15
  // final h lives in parity 0 (tag SEQLEN), entry e -> hbuf2[e*2]
  for (int k = tid; k < 1024; k += 256) {
    const float lv = (k < 512) ? hbuf2[(size_t)k * 2]         : hB[k - 512];
    const float rv = (k < 512) ? hbuf2[(size_t)(512 + k) * 2] : hB[512 + (k - 512)];
    vec[k] = lv * rv;
    vec[1024 + k] = fabsf(lv - rv);
  }
  __syncthreads();
  const int row = wg * 16 + (tid >> 4);
  const int ln = tid & 15;
  const float* wr = Wh + (size_t)row * 2048 + ln * 128;
  const float* vp = vec + ln * 128;
  float acc = 0.0f;
  #pragma unroll
  for (int k = 0; k < 128; k += 4) {
    float4 wv = *(const float4*)(wr + k);
    float4 vv = *(const float4*)(vp + k);
    acc += wv.x*vv.x + wv.y*vv.y + wv.z*vv.z + wv.w*vv.w;
  }
  #pragma unroll
  for (int msk = 1; msk < 16; msk <<= 1) acc += __shfl_xor(acc, msk, 64);
  if (ln == 0) sv[row] = 1.0f / (1.0f + expf(-(acc + bh[row])));
}

// ---------------- K3b: logits = Wp @ s + bp ; log_softmax ----------------
__global__ __launch_bounds__(256) void head2(
    const float* __restrict__ sv, const float* __restrict__ Wp,
    const float* __restrict__ bp, float* __restrict__ out)
{
  __shared__ float s_l[256];
  __shared__ float lg[5];
  const int tid = threadIdx.x;
  s_l[tid] = sv[tid];
  __syncthreads();
  if (tid < 5) {
    float acc = bp[tid];
    for (int k = 0; k < 256; ++k) acc += Wp[tid*256 + k] * s_l[k];
    lg[tid] = acc;
  }
  __syncthreads();
  if (tid == 0) {
    float mx = lg[0];
    #pragma unroll
    for (int i = 1; i < 5; ++i) mx = fmaxf(mx, lg[i]);
    float sum = 0.0f;
    #pragma unroll
    for (int i = 0; i < 5; ++i) sum += expf(lg[i] - mx);
    const float lse = mx + logf(sum);
    #pragma unroll
    for (int i = 0; i < 5; ++i) out[i] = lg[i] - lse;
  }
}

extern "C" void kernel_launch(void* const* d_in, const int* in_sizes, int n_in,
                              void* d_out, int out_size, void* d_ws, size_t ws_size,
                              hipStream_t stream) {
  const int*   l_ids = (const int*)d_in[0];
  const int*   r_ids = (const int*)d_in[1];
  const float* emb   = (const float*)d_in[2];
  const float* Wioux = (const float*)d_in[3];
  const float* bioux = (const float*)d_in[4];
  const float* Wiouh = (const float*)d_in[5];
  const float* biouh = (const float*)d_in[6];
  const float* Wfx   = (const float*)d_in[7];
  const float* bfx   = (const float*)d_in[8];
  const float* Wfh   = (const float*)d_in[9];
  const float* bfh   = (const float*)d_in[10];
  const float* Wh    = (const float*)d_in[11];
  const float* bh    = (const float*)d_in[12];
  const float* Wp    = (const float*)d_in[13];
  const float* bp    = (const float*)d_in[14];
  float* out = (float*)d_out;

  // workspace layout (floats): Gx [2*1024*2048], hbuf2 [2*1024*2], hB [1024], sv [256]
  float* gx    = (float*)d_ws;
  float* hbuf2 = gx + (size_t)2*1024*2048;
  float* hB    = hbuf2 + 4096;
  float* sv    = hB + 1024;

  // zero {h,tag} buffers + hB + sv each launch (graph-captured memset node)
  hipMemsetAsync(hbuf2, 0, (4096 + 1024 + 256) * sizeof(float), stream);

  gx_gemm<<<dim3(1024), dim3(256), 0, stream>>>(l_ids, r_ids, emb, Wioux, Wfx,
                                                bioux, biouh, bfx, bfh, gx);
  lstm_scan<<<dim3(32), dim3(256), 0, stream>>>(Wiouh, Wfh, gx, hbuf2, hB);
  head1<<<dim3(16), dim3(256), 0, stream>>>(hbuf2, hB, Wh, bh, sv);
  head2<<<dim3(1), dim3(256), 0, stream>>>(sv, Wp, bp, out);
  (void)in_sizes; (void)n_in; (void)out_size; (void)ws_size;
}